// Round 1
// baseline (499.593 us; speedup 1.0000x reference)
//
#include <hip/hip_runtime.h>

typedef unsigned int uint32;

__device__ __forceinline__ unsigned short f2bf(float f) {
  unsigned u = __float_as_uint(f);
  return (unsigned short)((u + 0x7FFFu + ((u >> 16) & 1u)) >> 16);
}

// k0: zero the 1024-elem output (harness poisons it) + detect edge_mask element size.
// Detection: if the first 1024 dwords are all in {0, 1, 0x3F800000} the mask is
// 4-byte elements (int32 or float32); otherwise it's 1-byte bools. A bool-byte
// mask would need 512 consecutive rows of arity==1 to fool this (P ~ (1/8)^512).
__global__ __launch_bounds__(256) void k0_detect_zero(const uint32* __restrict__ md,
                                                      int* __restrict__ flag,
                                                      float* __restrict__ out) {
  int t = blockIdx.x * blockDim.x + threadIdx.x;
  if (t < 1024) out[t] = 0.f;
  if (blockIdx.x == 0 && threadIdx.x < 64) {
    bool ok4 = true;
    for (int i = threadIdx.x; i < 1024; i += 64) {
      uint32 v = md[i];
      if (!(v == 0u || v == 1u || v == 0x3F800000u)) ok4 = false;
    }
    bool all4 = __all(ok4);
    if (threadIdx.x == 0) *flag = all4 ? 4 : 1;
  }
}

// k1: Wh = X @ W1, fp32 vector FMA, W1 (64KB) in LDS.
// One wave computes 2 rows; lane l computes cols 2l, 2l+1. Output stored bf16.
__global__ __launch_bounds__(256) void k1_matmul(const float* __restrict__ X,
                                                 const float* __restrict__ W,
                                                 unsigned* __restrict__ Wh, int NP) {
  __shared__ float sW[128 * 128];
  for (int i = threadIdx.x * 4; i < 128 * 128; i += blockDim.x * 4)
    *(float4*)&sW[i] = *(const float4*)&W[i];
  __syncthreads();
  const int lane = threadIdx.x & 63;
  const int wv = threadIdx.x >> 6;
  const int gw = blockIdx.x * 4 + wv;
  const int nw = gridDim.x * 4;
  for (int p = gw; p < NP; p += nw) {
    const int r0 = p * 2;
    const float* x0 = X + (size_t)r0 * 128;
    float a00 = 0.f, a01 = 0.f, a10 = 0.f, a11 = 0.f;
    #pragma unroll
    for (int k = 0; k < 128; k += 4) {
      float4 xa = *(const float4*)(x0 + k);
      float4 xb = *(const float4*)(x0 + 128 + k);
      #pragma unroll
      for (int kk = 0; kk < 4; ++kk) {
        float2 w = *(const float2*)&sW[(k + kk) * 128 + 2 * lane];
        float fa = (&xa.x)[kk], fb = (&xb.x)[kk];
        a00 = fmaf(fa, w.x, a00); a01 = fmaf(fa, w.y, a01);
        a10 = fmaf(fb, w.x, a10); a11 = fmaf(fb, w.y, a11);
      }
    }
    Wh[(size_t)r0 * 64 + lane]       = (unsigned)f2bf(a00) | ((unsigned)f2bf(a01) << 16);
    Wh[(size_t)(r0 + 1) * 64 + lane] = (unsigned)f2bf(a10) | ((unsigned)f2bf(a11) << 16);
  }
}

// k2: fused gather + score + softmax + weighted accumulate.
// One wave per edge (grid-stride). Lane = (g,t): group g in [0,8) owns arity slot g,
// lane t in [0,8) owns cols [t*16, t*16+16). Per-lane 16 fp32 accumulators,
// block LDS reduce, then atomicAdd into out[8][128].
__global__ __launch_bounds__(512) void k2_edges(const unsigned short* __restrict__ Wh,
                                                const int* __restrict__ elist,
                                                const unsigned char* __restrict__ maskb,
                                                const float* __restrict__ a1,
                                                const int* __restrict__ flag,
                                                float* __restrict__ out, int M) {
  __shared__ float sAcc[8][1024];
  const int lane = threadIdx.x & 63;
  const int wv = threadIdx.x >> 6;      // wave in block, 0..7
  const int g = lane >> 3, t = lane & 7;
  const int msz = *flag;
  const int* __restrict__ mask4 = (const int*)maskb;

  float a1r[16];
  #pragma unroll
  for (int j = 0; j < 16; j += 4) {
    float4 v = *(const float4*)&a1[t * 16 + j];
    a1r[j] = v.x; a1r[j + 1] = v.y; a1r[j + 2] = v.z; a1r[j + 3] = v.w;
  }
  float acc[16];
  #pragma unroll
  for (int j = 0; j < 16; ++j) acc[j] = 0.f;

  const int gw = blockIdx.x * 8 + wv;
  const int nw = gridDim.x * 8;
  for (int m = gw; m < M; m += nw) {
    const int e = m * 8 + g;
    const int idx = elist[e];
    const bool valid = (msz == 4) ? (mask4[e] != 0) : (maskb[e] != 0);
    float vals[16];
    float part = 0.f;
    if (valid) {
      const uint4* p = (const uint4*)(Wh + (size_t)idx * 128 + t * 16);
      uint4 u0 = p[0];
      uint4 u1 = p[1];
      vals[0]  = __uint_as_float(u0.x << 16); vals[1]  = __uint_as_float(u0.x & 0xFFFF0000u);
      vals[2]  = __uint_as_float(u0.y << 16); vals[3]  = __uint_as_float(u0.y & 0xFFFF0000u);
      vals[4]  = __uint_as_float(u0.z << 16); vals[5]  = __uint_as_float(u0.z & 0xFFFF0000u);
      vals[6]  = __uint_as_float(u0.w << 16); vals[7]  = __uint_as_float(u0.w & 0xFFFF0000u);
      vals[8]  = __uint_as_float(u1.x << 16); vals[9]  = __uint_as_float(u1.x & 0xFFFF0000u);
      vals[10] = __uint_as_float(u1.y << 16); vals[11] = __uint_as_float(u1.y & 0xFFFF0000u);
      vals[12] = __uint_as_float(u1.z << 16); vals[13] = __uint_as_float(u1.z & 0xFFFF0000u);
      vals[14] = __uint_as_float(u1.w << 16); vals[15] = __uint_as_float(u1.w & 0xFFFF0000u);
      #pragma unroll
      for (int j = 0; j < 16; ++j)
        part += fmaxf(vals[j], 0.2f * vals[j]) * a1r[j];  // leaky_relu(x) = max(x, 0.2x)
    } else {
      #pragma unroll
      for (int j = 0; j < 16; ++j) vals[j] = 0.f;
    }
    // score for slot g: reduce over the 8 lanes of the group
    part += __shfl_xor(part, 1);
    part += __shfl_xor(part, 2);
    part += __shfl_xor(part, 4);
    float s = valid ? part : -9e15f;
    // softmax across the 8 groups (slot 0 is always valid since arity >= 1)
    float mx = s;
    mx = fmaxf(mx, __shfl_xor(mx, 8));
    mx = fmaxf(mx, __shfl_xor(mx, 16));
    mx = fmaxf(mx, __shfl_xor(mx, 32));
    float ev = valid ? __expf(s - mx) : 0.f;
    float dn = ev;
    dn += __shfl_xor(dn, 8);
    dn += __shfl_xor(dn, 16);
    dn += __shfl_xor(dn, 32);
    const float att = __fdividef(ev, dn);
    #pragma unroll
    for (int j = 0; j < 16; ++j) acc[j] = fmaf(att, vals[j], acc[j]);
  }

  // per-wave accumulators -> LDS (col = slot*128 + t*16 + j, static indices only)
  #pragma unroll
  for (int j = 0; j < 16; ++j) sAcc[wv][g * 128 + t * 16 + j] = acc[j];
  __syncthreads();
  const int c = threadIdx.x * 2;
  float sx = 0.f, sy = 0.f;
  #pragma unroll
  for (int w = 0; w < 8; ++w) { sx += sAcc[w][c]; sy += sAcc[w][c + 1]; }
  atomicAdd(&out[c], sx);
  atomicAdd(&out[c + 1], sy);
}

extern "C" void kernel_launch(void* const* d_in, const int* in_sizes, int n_in,
                              void* d_out, int out_size, void* d_ws, size_t ws_size,
                              hipStream_t stream) {
  const float* node          = (const float*)d_in[0];
  // d_in[1] = edge_embs: unused by the reference computation
  const int* elist           = (const int*)d_in[2];
  const unsigned char* maskb = (const unsigned char*)d_in[3];
  const float* W1            = (const float*)d_in[4];
  const float* a1            = (const float*)d_in[5];
  float* out                 = (float*)d_out;

  const int N = in_sizes[0] / 128;
  const int M = in_sizes[2] / 8;

  unsigned* Wh = (unsigned*)d_ws;                       // bf16 Wh, N*128*2 bytes
  const size_t whBytes = (size_t)N * 128 * 2;
  int* flag = (int*)((char*)d_ws + whBytes);

  k0_detect_zero<<<4, 256, 0, stream>>>((const uint32*)maskb, flag, out);
  k1_matmul<<<1024, 256, 0, stream>>>(node, W1, Wh, N / 2);
  k2_edges<<<1024, 512, 0, stream>>>((const unsigned short*)Wh, elist, maskb, a1, flag, out, M);
}

// Round 2
// 105.048 us; speedup vs baseline: 4.7558x; 4.7558x over previous
//
#include <hip/hip_runtime.h>

typedef unsigned int uint32;
typedef __attribute__((ext_vector_type(8))) short short8v;  // 8 bf16 (4 VGPRs)
typedef __attribute__((ext_vector_type(4))) float f32x4;

__device__ __forceinline__ unsigned short f2bf(float f) {
  unsigned u = __float_as_uint(f);
  return (unsigned short)((u + 0x7FFFu + ((u >> 16) & 1u)) >> 16);
}

// k0: zero the 1024-elem output + detect edge_mask element size (1B bool vs 4B).
__global__ __launch_bounds__(256) void k0_detect_zero(const uint32* __restrict__ md,
                                                      int* __restrict__ flag,
                                                      float* __restrict__ out) {
  int t = blockIdx.x * blockDim.x + threadIdx.x;
  if (t < 1024) out[t] = 0.f;
  if (blockIdx.x == 0 && threadIdx.x < 64) {
    bool ok4 = true;
    for (int i = threadIdx.x; i < 1024; i += 64) {
      uint32 v = md[i];
      if (!(v == 0u || v == 1u || v == 0x3F800000u)) ok4 = false;
    }
    bool all4 = __all(ok4);
    if (threadIdx.x == 0) *flag = all4 ? 4 : 1;
  }
}

// k1: Wh = X @ W1 via mfma_f32_16x16x32_bf16.
// W1 pre-arranged once per block into bf16 B-fragments in LDS (32 frags x 64
// lanes x 16B, linear per-lane => conflict-free ds_read_b128). Each wave does a
// 16-row strip: 8 batched float4 loads of X, cvt to 4 A-frags, 32 MFMAs, bf16 store.
// A-frag: row = lane&15, k = kt*32 + (lane>>4)*8 + j (same bijection used for B,
// so the k-interleave detail cancels). C/D: col = lane&15, row = (lane>>4)*4 + reg.
__global__ __launch_bounds__(256) void k1_mfma(const float* __restrict__ X,
                                               const float* __restrict__ W,
                                               unsigned short* __restrict__ Wh,
                                               int N) {
  __shared__ short sB[2048 * 8];  // 32 KiB
  const int tid = threadIdx.x;
  for (int i = tid; i < 2048; i += 256) {
    const int frag = i >> 6, ln = i & 63;
    const int kt = frag >> 3, ct = frag & 7, p = ln >> 4, q = ln & 15;
    short8v v;
    #pragma unroll
    for (int j = 0; j < 8; ++j)
      v[j] = (short)f2bf(W[(kt * 32 + p * 8 + j) * 128 + ct * 16 + q]);
    *(short8v*)&sB[i * 8] = v;
  }
  __syncthreads();

  const int lane = tid & 63;
  const int p = lane >> 4, q = lane & 15;
  const int wave = blockIdx.x * 4 + (tid >> 6);
  const int nwaves = gridDim.x * 4;
  const int nstrips = (N + 15) >> 4;

  for (int s = wave; s < nstrips; s += nwaves) {
    const int row = s * 16 + q;
    const int rclamp = row < N ? row : (N - 1);
    const float* xr = X + (size_t)rclamp * 128 + p * 8;
    float4 L[8];
    #pragma unroll
    for (int kt = 0; kt < 4; ++kt) {
      L[2 * kt]     = *(const float4*)(xr + kt * 32);
      L[2 * kt + 1] = *(const float4*)(xr + kt * 32 + 4);
    }
    short8v A[4];
    #pragma unroll
    for (int kt = 0; kt < 4; ++kt) {
      #pragma unroll
      for (int j = 0; j < 4; ++j) {
        A[kt][j]     = (short)f2bf((&L[2 * kt].x)[j]);
        A[kt][j + 4] = (short)f2bf((&L[2 * kt + 1].x)[j]);
      }
    }
    f32x4 acc[8];
    #pragma unroll
    for (int ct = 0; ct < 8; ++ct) acc[ct] = (f32x4){0.f, 0.f, 0.f, 0.f};
    #pragma unroll
    for (int kt = 0; kt < 4; ++kt) {
      #pragma unroll
      for (int ct = 0; ct < 8; ++ct) {
        short8v b = *(const short8v*)&sB[((kt * 8 + ct) * 64 + lane) * 8];
        acc[ct] = __builtin_amdgcn_mfma_f32_16x16x32_bf16(A[kt], b, acc[ct], 0, 0, 0);
      }
    }
    const int r0 = s * 16 + p * 4;
    #pragma unroll
    for (int ct = 0; ct < 8; ++ct) {
      #pragma unroll
      for (int r = 0; r < 4; ++r) {
        const int rr = r0 + r;
        if (rr < N) Wh[(size_t)rr * 128 + ct * 16 + q] = f2bf(acc[ct][r]);
      }
    }
  }
}

// k2: fused gather + score + softmax + weighted accumulate (unchanged from R1, passing).
__global__ __launch_bounds__(512) void k2_edges(const unsigned short* __restrict__ Wh,
                                                const int* __restrict__ elist,
                                                const unsigned char* __restrict__ maskb,
                                                const float* __restrict__ a1,
                                                const int* __restrict__ flag,
                                                float* __restrict__ out, int M) {
  __shared__ float sAcc[8][1024];
  const int lane = threadIdx.x & 63;
  const int wv = threadIdx.x >> 6;
  const int g = lane >> 3, t = lane & 7;
  const int msz = *flag;
  const int* __restrict__ mask4 = (const int*)maskb;

  float a1r[16];
  #pragma unroll
  for (int j = 0; j < 16; j += 4) {
    float4 v = *(const float4*)&a1[t * 16 + j];
    a1r[j] = v.x; a1r[j + 1] = v.y; a1r[j + 2] = v.z; a1r[j + 3] = v.w;
  }
  float acc[16];
  #pragma unroll
  for (int j = 0; j < 16; ++j) acc[j] = 0.f;

  const int gw = blockIdx.x * 8 + wv;
  const int nw = gridDim.x * 8;
  for (int m = gw; m < M; m += nw) {
    const int e = m * 8 + g;
    const int idx = elist[e];
    const bool valid = (msz == 4) ? (mask4[e] != 0) : (maskb[e] != 0);
    float vals[16];
    float part = 0.f;
    if (valid) {
      const uint4* ptr = (const uint4*)(Wh + (size_t)idx * 128 + t * 16);
      uint4 u0 = ptr[0];
      uint4 u1 = ptr[1];
      vals[0]  = __uint_as_float(u0.x << 16); vals[1]  = __uint_as_float(u0.x & 0xFFFF0000u);
      vals[2]  = __uint_as_float(u0.y << 16); vals[3]  = __uint_as_float(u0.y & 0xFFFF0000u);
      vals[4]  = __uint_as_float(u0.z << 16); vals[5]  = __uint_as_float(u0.z & 0xFFFF0000u);
      vals[6]  = __uint_as_float(u0.w << 16); vals[7]  = __uint_as_float(u0.w & 0xFFFF0000u);
      vals[8]  = __uint_as_float(u1.x << 16); vals[9]  = __uint_as_float(u1.x & 0xFFFF0000u);
      vals[10] = __uint_as_float(u1.y << 16); vals[11] = __uint_as_float(u1.y & 0xFFFF0000u);
      vals[12] = __uint_as_float(u1.z << 16); vals[13] = __uint_as_float(u1.z & 0xFFFF0000u);
      vals[14] = __uint_as_float(u1.w << 16); vals[15] = __uint_as_float(u1.w & 0xFFFF0000u);
      #pragma unroll
      for (int j = 0; j < 16; ++j)
        part += fmaxf(vals[j], 0.2f * vals[j]) * a1r[j];
    } else {
      #pragma unroll
      for (int j = 0; j < 16; ++j) vals[j] = 0.f;
    }
    part += __shfl_xor(part, 1);
    part += __shfl_xor(part, 2);
    part += __shfl_xor(part, 4);
    float s = valid ? part : -9e15f;
    float mx = s;
    mx = fmaxf(mx, __shfl_xor(mx, 8));
    mx = fmaxf(mx, __shfl_xor(mx, 16));
    mx = fmaxf(mx, __shfl_xor(mx, 32));
    float ev = valid ? __expf(s - mx) : 0.f;
    float dn = ev;
    dn += __shfl_xor(dn, 8);
    dn += __shfl_xor(dn, 16);
    dn += __shfl_xor(dn, 32);
    const float att = __fdividef(ev, dn);
    #pragma unroll
    for (int j = 0; j < 16; ++j) acc[j] = fmaf(att, vals[j], acc[j]);
  }

  #pragma unroll
  for (int j = 0; j < 16; ++j) sAcc[wv][g * 128 + t * 16 + j] = acc[j];
  __syncthreads();
  const int c = threadIdx.x * 2;
  float sx = 0.f, sy = 0.f;
  #pragma unroll
  for (int w = 0; w < 8; ++w) { sx += sAcc[w][c]; sy += sAcc[w][c + 1]; }
  atomicAdd(&out[c], sx);
  atomicAdd(&out[c + 1], sy);
}

extern "C" void kernel_launch(void* const* d_in, const int* in_sizes, int n_in,
                              void* d_out, int out_size, void* d_ws, size_t ws_size,
                              hipStream_t stream) {
  const float* node          = (const float*)d_in[0];
  const int* elist           = (const int*)d_in[2];
  const unsigned char* maskb = (const unsigned char*)d_in[3];
  const float* W1            = (const float*)d_in[4];
  const float* a1            = (const float*)d_in[5];
  float* out                 = (float*)d_out;

  const int N = in_sizes[0] / 128;
  const int M = in_sizes[2] / 8;

  unsigned short* Wh = (unsigned short*)d_ws;           // bf16 Wh, N*128*2 bytes
  const size_t whBytes = (size_t)N * 128 * 2;
  int* flag = (int*)((char*)d_ws + whBytes);

  k0_detect_zero<<<4, 256, 0, stream>>>((const uint32*)maskb, flag, out);
  k1_mfma<<<784, 256, 0, stream>>>(node, W1, Wh, N);
  k2_edges<<<1024, 512, 0, stream>>>((const unsigned short*)Wh, elist, maskb, a1, flag, out, M);
}